// Round 18
// baseline (256.477 us; speedup 1.0000x reference)
//
#include <hip/hip_runtime.h>
#include <stdint.h>
#include <math.h>

// ---------------------------------------------------------------------------
// Transformer block (B=2, S=2048, D=1024, H=16, hd=64, F=4096), post-LN.
// bf16 MFMA for all matmuls, fp32 accumulate. Threshold is 2% of |ref|max.
// GEMMs: 128x128 tile, BK=64, m97 2-barrier loop, 4 blocks/CU; all staging
//        pointers / LDS offsets hoisted out of the K-loop (VALU reduction).
// Attention: no-max softmax via exp2 (scale pre-folded into Q); 8-wave split
//        pairs; counted-vmcnt pipeline; hoisted staging pointers.
// ---------------------------------------------------------------------------

typedef __attribute__((ext_vector_type(4))) float f32x4;
typedef __attribute__((ext_vector_type(8))) short s16x8;

__device__ __forceinline__ float bf2f(short s){
  unsigned u = ((unsigned)(unsigned short)s) << 16;
  return __builtin_bit_cast(float, u);
}
__device__ __forceinline__ short f2bf(float f){
  unsigned u = __builtin_bit_cast(unsigned, f);
  unsigned r = (u + 0x7fffu + ((u >> 16) & 1u)) >> 16;   // RNE
  return (short)(unsigned short)r;
}

__device__ __forceinline__ void gload_lds16(const void* gp, void* lp){
  __builtin_amdgcn_global_load_lds(
      (__attribute__((address_space(1))) void*)const_cast<void*>(gp),
      (__attribute__((address_space(3))) void*)lp,
      16, 0, 0);
}

#define QSCALE 0.18033688f   // 0.125 * log2(e): folded into Q so attn uses exp2

// ---------------- elementwise f32 -> bf16 ----------------------------------
__global__ void cvt_f32_bf16(const float* __restrict__ in, short* __restrict__ out, int n){
  int i = (blockIdx.x * blockDim.x + threadIdx.x) * 4;
  if (i < n){
    float4 v = *(const float4*)(in + i);
    short4 o;
    o.x = f2bf(v.x); o.y = f2bf(v.y); o.z = f2bf(v.z); o.w = f2bf(v.w);
    *(short4*)(out + i) = o;
  }
}

// ---------------- weight transpose+convert: in[R][C] f32 -> out[C][R] bf16 --
__global__ __launch_bounds__(256) void wtrans(const float* __restrict__ in,
                                              short* __restrict__ out, int R, int C){
  __shared__ float tile[32][33];
  int c0 = blockIdx.x * 32, r0 = blockIdx.y * 32;
  int tx = threadIdx.x, ty = threadIdx.y;        // block (32,8)
  #pragma unroll
  for (int j = 0; j < 4; ++j)
    tile[ty + j*8][tx] = in[(size_t)(r0 + ty + j*8) * C + c0 + tx];
  __syncthreads();
  #pragma unroll
  for (int j = 0; j < 4; ++j)
    out[(size_t)(c0 + ty + j*8) * R + r0 + tx] = f2bf(tile[tx][ty + j*8]);
}

// ---------------- V transpose: qkv[b*2048+s][2048+h*64+d] -> vt[(bh*64+d)][s]
__global__ __launch_bounds__(256) void vtrans(const short* __restrict__ qkv,
                                              short* __restrict__ vt){
  __shared__ short tile[32][33];
  int bh = blockIdx.z; int b = bh >> 4, h = bh & 15;
  int s0 = blockIdx.x * 32, d0 = blockIdx.y * 32;
  int tx = threadIdx.x, ty = threadIdx.y;
  #pragma unroll
  for (int j = 0; j < 4; ++j)
    tile[ty + j*8][tx] = qkv[(size_t)(b*2048 + s0 + ty + j*8) * 3072 + 2048 + h*64 + d0 + tx];
  __syncthreads();
  #pragma unroll
  for (int j = 0; j < 4; ++j)
    vt[(size_t)(bh*64 + d0 + ty + j*8) * 2048 + s0 + tx] = tile[tx][ty + j*8];
}

// ---------------- GEMM: C[M][N] = A[M][K](bf16) @ BT[N][K](bf16)^T ---------
// 128x128 tile, BK=64, 4 waves (2x2), m97 2-barrier loop, 4 blocks/CU.
// EPI: 0 = bf16 (acc+bias), Q-cols (<1024) pre-scaled by QSCALE   (qkv)
//      2 = gelu(acc+bias) bf16                                    (fc)
//      4 = raw bf16 partial to o[blockIdx.z]   (split-K; bias in LN fuse)
// All staging pointers advance by += GBK per tile; ds_read offsets hoisted.
#define GBM 128
#define GBN 128
#define GBK 64

__global__ __launch_bounds__(256, 4) void gemm_bf16(
    const short* __restrict__ A, const short* __restrict__ BT,
    const float* __restrict__ bias,
    void* __restrict__ out, void* __restrict__ out2,
    void* __restrict__ out3, void* __restrict__ out4,
    int M, int N, int K, int EPI, int KS)
{
  __shared__ __attribute__((aligned(16))) short smem[GBM*GBK*2];  // 32 KB
  short* sA = smem;                 // 16 KB, rows of 64 shorts, XOR-swizzled slots
  short* sB = smem + GBM*GBK;       // 16 KB
  const int t = threadIdx.x;
  const int lane = t & 63;
  const int w = t >> 6;
  const int wr = w >> 1, wc = w & 1;            // 2x2 wave grid, each wave 64x64
  const int lrow = lane & 15;
  const int lk = lane >> 4;

  // bijective XCD-chunked remap: XCD x computes a contiguous wg range
  const int gx = gridDim.x;
  const int nwg = gx * gridDim.y;               // all grids here: nwg % 8 == 0
  const int P = blockIdx.y * gx + blockIdx.x;
  const int wg = (P & 7) * (nwg >> 3) + (P >> 3);
  const int m0 = (wg / gx) * GBM, n0 = (wg % gx) * GBN;

  const int Kspl = K / KS;
  const int kbeg = blockIdx.z * Kspl;
  const int NT = Kspl / GBK;

  // hoisted staging pointers (advance += GBK per K-tile) and LDS dests
  const short* gA[4]; const short* gB[4]; int ldo[4];
  #pragma unroll
  for (int r = 0; r < 4; ++r){
    int o = r * 4096 + t * 16;                  // linear LDS byte offset
    int row = o >> 7;                           // 128 B per row
    int lsl = ((o >> 4) & 7) ^ (row & 7);       // inverse-swizzled source chunk
    ldo[r] = o;
    gA[r] = A  + (size_t)(m0 + row) * K + kbeg + lsl * 8;
    gB[r] = BT + (size_t)(n0 + row) * K + kbeg + lsl * 8;
  }

  // hoisted swizzled ds_read offsets (in shorts)
  int aoff[2][4], boff[2][4];
  #pragma unroll
  for (int kc = 0; kc < 2; ++kc){
    #pragma unroll
    for (int i = 0; i < 4; ++i){
      int ra = wr*64 + i*16 + lrow;
      aoff[kc][i] = ra*64 + ((kc*4 + lk) ^ (ra & 7))*8;
      int rb = wc*64 + i*16 + lrow;
      boff[kc][i] = rb*64 + ((kc*4 + lk) ^ (rb & 7))*8;
    }
  }

  f32x4 acc[4][4] = {};

  for (int tt = 0; tt < NT; ++tt){
    __syncthreads();                            // prior reads done before overwrite
    #pragma unroll
    for (int r = 0; r < 4; ++r) gload_lds16(gA[r], (char*)sA + ldo[r]);
    #pragma unroll
    for (int r = 0; r < 4; ++r) gload_lds16(gB[r], (char*)sB + ldo[r]);
    #pragma unroll
    for (int r = 0; r < 4; ++r){ gA[r] += GBK; gB[r] += GBK; }
    __syncthreads();                            // drains vmcnt before barrier

    #pragma unroll
    for (int kc = 0; kc < 2; ++kc){
      s16x8 af[4], bf[4];
      #pragma unroll
      for (int rt = 0; rt < 4; ++rt) af[rt] = *(const s16x8*)&sA[aoff[kc][rt]];
      #pragma unroll
      for (int ct = 0; ct < 4; ++ct) bf[ct] = *(const s16x8*)&sB[boff[kc][ct]];
      #pragma unroll
      for (int rt = 0; rt < 4; ++rt)
        #pragma unroll
        for (int ct = 0; ct < 4; ++ct)
          acc[rt][ct] = __builtin_amdgcn_mfma_f32_16x16x32_bf16(af[rt], bf[ct], acc[rt][ct], 0, 0, 0);
    }
  }

  // ---- epilogue: bf16 values -> LDS re-layout -> coalesced dwordx4 stores
  __syncthreads();                              // all waves done reading sA/sB
  #pragma unroll
  for (int rt = 0; rt < 4; ++rt){
    #pragma unroll
    for (int ct = 0; ct < 4; ++ct){
      #pragma unroll
      for (int r = 0; r < 4; ++r){
        int row = wr*64 + rt*16 + lk*4 + r;     // C/D: row=(lane>>4)*4+reg
        int col = wc*64 + ct*16 + lrow;         //      col=lane&15
        float v = acc[rt][ct][r];
        if (EPI != 4){
          v += bias[n0 + col];
          if (EPI == 0){
            if (n0 + col < 1024) v *= QSCALE;   // fold attn scale*log2e into Q
          } else {
            v = 0.5f * v * (1.0f + erff(v * 0.70710678118654752f));  // gelu
          }
        }
        int off = row*256 + ((col*2) ^ (((row >> 2) & 7) << 5));  // swizzled
        *(short*)((char*)smem + off) = f2bf(v);
      }
    }
  }
  __syncthreads();
  void* pz = (blockIdx.z == 0) ? out : (blockIdx.z == 1) ? out2
           : (blockIdx.z == 2) ? out3 : out4;
  short* outp = (EPI == 4) ? (short*)pz : (short*)out;
  #pragma unroll
  for (int j = 0; j < 8; ++j){
    int L = j*4096 + t*16;                      // logical byte offset in tile
    int row = L >> 8;                           // 256 B per logical row
    int cb  = L & 255;
    int phys = row*256 + (cb ^ (((row >> 2) & 7) << 5));   // 16B chunk intact
    s16x8 vv = *(const s16x8*)((char*)smem + phys);
    *(s16x8*)(outp + (size_t)(m0 + row) * N + n0 + (cb >> 1)) = vv;
  }
}

// ---------------- attention (causal), no-max softmax, 8-wave split pairs ----
// Block = 512 threads (8 waves). Waves 0-3 own q-tile A=pairi (rows w*16);
// waves 4-7 own q-tile B=31-pairi. ONE k-loop over tiles 0..31-pairi; A-waves
// compute only while ktile <= pairi (barriers always joint). K/V tiles staged
// once per tile (1 round each at 512 threads), counted vmcnt(2) pipeline.
// Staging pointers hoisted (advance per tile); read offsets hoisted.
// 512 blocks; all blocks of one (b,h) share an XCD (P%8); blocks P and P+256
// have complementary pairi -> per-CU tile cost constant (49).
__global__ __launch_bounds__(512, 4) void attn_kernel(
    const short* __restrict__ qkv, const short* __restrict__ vt,
    short* __restrict__ ob)
{
  const int P = blockIdx.x;
  const int xcd = P & 7;
  const int idx = P >> 3;               // 0..63
  const int raw = idx & 15;
  const int grp = idx >> 4;             // 0..3
  const int pairi = (grp & 2) ? (15 - raw) : raw;   // CU-pair balancing
  const int bh = xcd + (grp << 3);
  const int b = bh >> 4, h = bh & 15;
  const int t  = threadIdx.x;
  const int lane = t & 63;
  const int w = t >> 6;                 // 0..7
  const int lrow = lane & 15, lk = lane >> 4;

  __shared__ short sK[2][64*64];        // 2 x 8 KB, rows of 64 shorts, XOR-swizzled
  __shared__ short sV[2][64*64];        // 2 x 8 KB
  __shared__ short sP[8][16][68];       // per-wave P tile, +4 shorts pad

  s16x8 bones;                          // all-ones bf16 B fragment
  #pragma unroll
  for (int i = 0; i < 8; ++i) bones[i] = (short)0x3F80;

  // hoisted staging pointers: one 16B chunk per thread per tile
  const int so = t*16;                  // LDS byte offset (8 KB tile, 512 thr)
  {
  }
  const int srow = so >> 7;             // 128 B per row
  const int slsl = ((so >> 4) & 7) ^ (srow & 7);
  const short* kptr = qkv + (size_t)(b*2048)*3072 + 1024 + h*64
                      + (size_t)srow*3072 + slsl*8;
  const short* vptr = vt + (size_t)((b*16 + h)*64 + srow)*2048 + slsl*8;

  // hoisted swizzled read offsets (K and V tiles share layout)
  int kvoff[2][4];
  #pragma unroll
  for (int kc = 0; kc < 2; ++kc)
    #pragma unroll
    for (int i = 0; i < 4; ++i){
      int row = i*16 + lrow;
      kvoff[kc][i] = row*64 + ((kc*4 + lk) ^ (row & 7))*8;
    }

  const int set = w >> 2;               // 0 = A (short), 1 = B (long)
  const int qt = set ? (31 - pairi) : pairi;
  const int qbase = qt*64 + (w & 3)*16;
  const int ntSelf = qt + 1;            // this wave computes tiles < ntSelf
  const int ntB = 32 - pairi;           // loop bound (long set's tile count)

  s16x8 aq[2];
  #pragma unroll
  for (int kc = 0; kc < 2; ++kc)
    aq[kc] = *(const s16x8*)(qkv + (size_t)(b*2048 + qbase + lrow)*3072 + h*64 + kc*32 + lk*8);

  f32x4 oacc[4] = {};
  f32x4 sumacc = {};

  auto stage = [&](int buf){
    gload_lds16(kptr, (char*)sK[buf] + so);
    gload_lds16(vptr, (char*)sV[buf] + so);
    kptr += 64*3072;                    // next k-tile: +64 K-rows
    vptr += 64;                         // next k-tile: +64 V^T cols
  };

  stage(0);                             // prologue (2 loads in flight)
  int cur = 0;

  for (int ktile = 0; ktile < ntB; ++ktile){
    const int k0 = ktile * 64;
    if (ktile + 1 < ntB){
      stage(cur ^ 1);                   // issue next tile's 2 loads
      asm volatile("s_waitcnt vmcnt(2)" ::: "memory");   // tile `cur` landed
    } else {
      asm volatile("s_waitcnt vmcnt(0)" ::: "memory");
    }
    __builtin_amdgcn_s_barrier();       // acquire: all waves' tile-cur loads visible
    __builtin_amdgcn_sched_barrier(0);

    if (ktile < ntSelf){                // wave-uniform branch
      f32x4 sacc[4] = {};
      __builtin_amdgcn_s_setprio(1);
      #pragma unroll
      for (int kc = 0; kc < 2; ++kc){
        #pragma unroll
        for (int ct = 0; ct < 4; ++ct){
          s16x8 bk = *(const s16x8*)&sK[cur][kvoff[kc][ct]];
          sacc[ct] = __builtin_amdgcn_mfma_f32_16x16x32_bf16(aq[kc], bk, sacc[ct], 0, 0, 0);
        }
      }
      __builtin_amdgcn_s_setprio(0);

      const bool need_mask = (k0 + 63 > qbase);
      #pragma unroll
      for (int ct = 0; ct < 4; ++ct){
        #pragma unroll
        for (int r = 0; r < 4; ++r){
          float v = sacc[ct][r];                        // scale pre-folded in Q
          if (need_mask){
            int qi = qbase + lk*4 + r;
            int ki = k0 + ct*16 + lrow;
            if (ki > qi) v = -100000.0f;                // exp2 -> exactly 0
          }
          sP[w][lk*4 + r][ct*16 + lrow] = f2bf(exp2f(v));
        }
      }

      s16x8 pa[2];
      #pragma unroll
      for (int kc = 0; kc < 2; ++kc)
        pa[kc] = *(const s16x8*)&sP[w][lrow][kc*32 + lk*8];
      __builtin_amdgcn_s_setprio(1);
      #pragma unroll
      for (int dt = 0; dt < 4; ++dt){
        #pragma unroll
        for (int kc = 0; kc < 2; ++kc){
          s16x8 bv = *(const s16x8*)&sV[cur][kvoff[kc][dt]];
          oacc[dt] = __builtin_amdgcn_mfma_f32_16x16x32_bf16(pa[kc], bv, oacc[dt], 0, 0, 0);
        }
      }
      #pragma unroll
      for (int kc = 0; kc < 2; ++kc)
        sumacc = __builtin_amdgcn_mfma_f32_16x16x32_bf16(pa[kc], bones, sumacc, 0, 0, 0);
      __builtin_amdgcn_s_setprio(0);
    }

    __builtin_amdgcn_sched_barrier(0);
    __builtin_amdgcn_s_barrier();       // release: all waves done reading `cur`
    cur ^= 1;
  }

  #pragma unroll
  for (int r = 0; r < 4; ++r){
    float inv = 1.0f / sumacc[r];
    int row = b*2048 + qbase + lk*4 + r;
    #pragma unroll
    for (int dt = 0; dt < 4; ++dt){
      int col = h*64 + dt*16 + lrow;
      ob[(size_t)row * 1024 + col] = f2bf(oacc[dt][r] * inv);
    }
  }
}

// -------- LN fused with split-K4 reduce + residual --------------------------
// v = p0+p1+p2+p3 (bf16 partials) + bias + (resid_bf | resid_f); out = LN(v)
__global__ __launch_bounds__(256) void ln_fused(
    const short* __restrict__ p0, const short* __restrict__ p1,
    const short* __restrict__ p2, const short* __restrict__ p3,
    const float* __restrict__ bias,
    const short* __restrict__ resid_bf, const float* __restrict__ resid_f,
    const float* __restrict__ g, const float* __restrict__ b,
    void* __restrict__ out, int bf16_out)
{
  const int row = blockIdx.x;
  const int t = threadIdx.x;
  const size_t base = (size_t)row*1024 + t*4;
  short4 a0 = *(const short4*)(p0 + base);
  short4 a1 = *(const short4*)(p1 + base);
  short4 a2 = *(const short4*)(p2 + base);
  short4 a3 = *(const short4*)(p3 + base);
  float4 bi = *(const float4*)(bias + t*4);
  float r0, r1, r2, r3;
  if (resid_bf){
    short4 rr = *(const short4*)(resid_bf + base);
    r0 = bf2f(rr.x); r1 = bf2f(rr.y); r2 = bf2f(rr.z); r3 = bf2f(rr.w);
  } else {
    float4 rr = *(const float4*)(resid_f + base);
    r0 = rr.x; r1 = rr.y; r2 = rr.z; r3 = rr.w;
  }
  float v0 = bf2f(a0.x) + bf2f(a1.x) + bf2f(a2.x) + bf2f(a3.x) + bi.x + r0;
  float v1 = bf2f(a0.y) + bf2f(a1.y) + bf2f(a2.y) + bf2f(a3.y) + bi.y + r1;
  float v2 = bf2f(a0.z) + bf2f(a1.z) + bf2f(a2.z) + bf2f(a3.z) + bi.z + r2;
  float v3 = bf2f(a0.w) + bf2f(a1.w) + bf2f(a2.w) + bf2f(a3.w) + bi.w + r3;
  float s = v0 + v1 + v2 + v3;
  float q = v0*v0 + v1*v1 + v2*v2 + v3*v3;
  #pragma unroll
  for (int off = 1; off < 64; off <<= 1){
    s += __shfl_xor(s, off, 64);
    q += __shfl_xor(q, off, 64);
  }
  __shared__ float ss[4], sq[4];
  if ((t & 63) == 0){ ss[t >> 6] = s; sq[t >> 6] = q; }
  __syncthreads();
  s = ss[0] + ss[1] + ss[2] + ss[3];
  q = sq[0] + sq[1] + sq[2] + sq[3];
  float mu = s * (1.0f/1024.0f);
  float var = q * (1.0f/1024.0f) - mu*mu;
  float rs = rsqrtf(var + 1e-5f);
  float4 gg = *(const float4*)(g + t*4);
  float4 bb = *(const float4*)(b + t*4);
  float o0 = (v0 - mu)*rs*gg.x + bb.x;
  float o1 = (v1 - mu)*rs*gg.y + bb.y;
  float o2 = (v2 - mu)*rs*gg.z + bb.z;
  float o3 = (v3 - mu)*rs*gg.w + bb.w;
  if (bf16_out){
    short4 o; o.x = f2bf(o0); o.y = f2bf(o1); o.z = f2bf(o2); o.w = f2bf(o3);
    *(short4*)((short*)out + base) = o;
  } else {
    float4 o = {o0, o1, o2, o3};
    *(float4*)((float*)out + base) = o;
  }
}

// ---------------------------------------------------------------------------
extern "C" void kernel_launch(void* const* d_in, const int* in_sizes, int n_in,
                              void* d_out, int out_size, void* d_ws, size_t ws_size,
                              hipStream_t stream) {
  const float* x      = (const float*)d_in[0];
  const float* w_attn = (const float*)d_in[1];
  const float* b_attn = (const float*)d_in[2];
  const float* w_o    = (const float*)d_in[3];
  const float* b_o    = (const float*)d_in[4];
  const float* ln1_g  = (const float*)d_in[5];
  const float* ln1_b  = (const float*)d_in[6];
  const float* w_fc   = (const float*)d_in[7];
  const float* b_fc   = (const float*)d_in[8];
  const float* w_pr   = (const float*)d_in[9];
  const float* b_pr   = (const float*)d_in[10];
  const float* ln2_g  = (const float*)d_in[11];
  const float* ln2_b  = (const float*)d_in[12];

  char* ws = (char*)d_ws;
  const size_t MB = 1048576;
  // lifetimes: high-water 96 MiB
  short* waT  = (short*)(ws + 0);          // 6 MiB  (steps 2-6)
  short* wfT  = (short*)(ws + 6*MB);       // 8 MiB  (steps 2-11)
  short* wpT  = (short*)(ws + 14*MB);      // 8 MiB  (steps 2-12)
  short* woT  = (short*)(ws + 22*MB);      // 2 MiB  (steps 2-9)
  short* xb   = (short*)(ws + 24*MB);      // 8 MiB  (steps 1-6)
  short* vt   = (short*)(ws + 24*MB);      // 8 MiB  (steps 7-8)
  short* pp2  = (short*)(ws + 24*MB);      // 8 MiB  (steps 9-10, 12-13)
  short* qkvb = (short*)(ws + 32*MB);      // 24 MiB (steps 6-8)
  short* fb   = (short*)(ws + 32*MB);      // 32 MiB (steps 11-12)
  short* ob   = (short*)(ws + 56*MB);      // 8 MiB  (steps 8-9)
  short* pp0  = (short*)(ws + 64*MB);      // 8 MiB  (steps 9-10, 12-13)
  short* pp1  = (short*)(ws + 72*MB);      // 8 MiB
  short* nb   = (short*)(ws + 80*MB);      // 8 MiB  (steps 10-13)
  short* pp3  = (short*)(ws + 88*MB);      // 8 MiB  (steps 9-10, 12-13)

  const int M = 4096;

  // 1. x -> bf16
  cvt_f32_bf16<<<dim3(M*1024/1024), dim3(256), 0, stream>>>(x, xb, M*1024);
  // 2-5. weight transposes (f32 [K][N] -> bf16 [N][K])
  wtrans<<<dim3(3072/32, 1024/32), dim3(32,8), 0, stream>>>(w_attn, waT, 1024, 3072);
  wtrans<<<dim3(1024/32, 1024/32), dim3(32,8), 0, stream>>>(w_o,   woT, 1024, 1024);
  wtrans<<<dim3(4096/32, 1024/32), dim3(32,8), 0, stream>>>(w_fc,  wfT, 1024, 4096);
  wtrans<<<dim3(1024/32, 4096/32), dim3(32,8), 0, stream>>>(w_pr,  wpT, 4096, 1024);
  // 6. qkv = x @ w_attn + b_attn (bf16 out, Q pre-scaled); 24x32 = 768 blocks
  gemm_bf16<<<dim3(3072/GBN, M/GBM), dim3(256), 0, stream>>>(
      xb, waT, b_attn, qkvb, nullptr, nullptr, nullptr, M, 3072, 1024, 0, 1);
  // 7. vt = transpose of V per (b,h)
  vtrans<<<dim3(2048/32, 64/32, 32), dim3(32,8), 0, stream>>>(qkvb, vt);
  // 8. attention -> ob (bf16); 8-wave split pairs, 512 blocks x 512 threads
  attn_kernel<<<dim3(512), dim3(512), 0, stream>>>(qkvb, vt, ob);
  // 9. o-proj split-K4: pp0..3 = ob @ w_o partials (bf16); 8x32x4 = 1024 blocks
  gemm_bf16<<<dim3(1024/GBN, M/GBM, 4), dim3(256), 0, stream>>>(
      ob, woT, nullptr, pp0, pp1, pp2, pp3, M, 1024, 1024, 4, 4);
  // 10. n = LN(pp* + b_o + x) -> nb (bf16)
  ln_fused<<<dim3(M), dim3(256), 0, stream>>>(pp0, pp1, pp2, pp3, b_o,
                                              nullptr, x, ln1_g, ln1_b, nb, 1);
  // 11. f = gelu(n @ w_fc + b_fc) -> fb (bf16); 32x32 = 1024 blocks (4/CU)
  gemm_bf16<<<dim3(4096/GBN, M/GBM), dim3(256), 0, stream>>>(
      nb, wfT, b_fc, fb, nullptr, nullptr, nullptr, M, 4096, 1024, 2, 1);
  // 12. r2 split-K4: pp0..3 = fb @ w_pr partials (bf16); 8x32x4 = 1024 blocks
  gemm_bf16<<<dim3(1024/GBN, M/GBM, 4), dim3(256), 0, stream>>>(
      fb, wpT, nullptr, pp0, pp1, pp2, pp3, M, 1024, 4096, 4, 4);
  // 13. h = LN(pp* + b_pr + nb) -> d_out (f32)
  ln_fused<<<dim3(M), dim3(256), 0, stream>>>(pp0, pp1, pp2, pp3, b_pr,
                                              nb, nullptr, ln2_g, ln2_b, d_out, 0);
}

// Round 19
// 249.018 us; speedup vs baseline: 1.0300x; 1.0300x over previous
//
#include <hip/hip_runtime.h>
#include <stdint.h>
#include <math.h>

// ---------------------------------------------------------------------------
// Transformer block (B=2, S=2048, D=1024, H=16, hd=64, F=4096), post-LN.
// bf16 MFMA for all matmuls, fp32 accumulate. Threshold is 2% of |ref|max.
// GEMMs: 128x128 tile, BK=64, m97 2-barrier loop, 4 blocks/CU (plateau optimum
//        after 6 structure probes); LDS re-layout epilogue, dwordx4 stores.
// Attention: no-max softmax via exp2 (scale pre-folded into Q); 8-wave split
//        pairs; counted-vmcnt pipeline (plateau optimum after 5 probes).
// Prep: single consolidated kernel (cvt + 4 weight transposes) — removes 4
//        dispatch boundaries.
// ---------------------------------------------------------------------------

typedef __attribute__((ext_vector_type(4))) float f32x4;
typedef __attribute__((ext_vector_type(8))) short s16x8;

__device__ __forceinline__ float bf2f(short s){
  unsigned u = ((unsigned)(unsigned short)s) << 16;
  return __builtin_bit_cast(float, u);
}
__device__ __forceinline__ short f2bf(float f){
  unsigned u = __builtin_bit_cast(unsigned, f);
  unsigned r = (u + 0x7fffu + ((u >> 16) & 1u)) >> 16;   // RNE
  return (short)(unsigned short)r;
}

__device__ __forceinline__ void gload_lds16(const void* gp, void* lp){
  __builtin_amdgcn_global_load_lds(
      (__attribute__((address_space(1))) void*)const_cast<void*>(gp),
      (__attribute__((address_space(3))) void*)lp,
      16, 0, 0);
}

#define QSCALE 0.18033688f   // 0.125 * log2(e): folded into Q so attn uses exp2

// ---------------- consolidated prep: cvt x->bf16 + 4 weight transposes -----
// blockIdx regions: [0,4096) cvt | [4096,7168) waT | [7168,8192) woT
//                   [8192,12288) wfT | [12288,16384) wpT
__global__ __launch_bounds__(256) void prep_all(
    const float* __restrict__ x, const float* __restrict__ w_attn,
    const float* __restrict__ w_o, const float* __restrict__ w_fc,
    const float* __restrict__ w_pr,
    short* __restrict__ xb, short* __restrict__ waT, short* __restrict__ woT,
    short* __restrict__ wfT, short* __restrict__ wpT)
{
  const int bid = blockIdx.x;
  const int t = threadIdx.x;
  if (bid < 4096){                              // cvt region: 1024 elems/block
    int i = bid*1024 + t*4;
    float4 v = *(const float4*)(x + i);
    short4 o; o.x = f2bf(v.x); o.y = f2bf(v.y); o.z = f2bf(v.z); o.w = f2bf(v.w);
    *(short4*)(xb + i) = o;
    return;
  }
  const float* in; short* out; int R, C, q;
  if (bid < 7168)      { in = w_attn; out = waT; R = 1024; C = 3072; q = bid - 4096; }
  else if (bid < 8192) { in = w_o;    out = woT; R = 1024; C = 1024; q = bid - 7168; }
  else if (bid < 12288){ in = w_fc;   out = wfT; R = 1024; C = 4096; q = bid - 8192; }
  else                 { in = w_pr;   out = wpT; R = 4096; C = 1024; q = bid - 12288; }
  const int ctiles = C >> 5;
  const int r0 = (q / ctiles) * 32, c0 = (q % ctiles) * 32;
  __shared__ float tile[32][33];
  const int tx = t & 31, ty = t >> 5;           // 32x8
  #pragma unroll
  for (int j = 0; j < 4; ++j)
    tile[ty + j*8][tx] = in[(size_t)(r0 + ty + j*8) * C + c0 + tx];
  __syncthreads();
  #pragma unroll
  for (int j = 0; j < 4; ++j)
    out[(size_t)(c0 + ty + j*8) * R + r0 + tx] = f2bf(tile[tx][ty + j*8]);
}

// ---------------- V transpose: qkv[b*2048+s][2048+h*64+d] -> vt[(bh*64+d)][s]
__global__ __launch_bounds__(256) void vtrans(const short* __restrict__ qkv,
                                              short* __restrict__ vt){
  __shared__ short tile[32][33];
  int bh = blockIdx.z; int b = bh >> 4, h = bh & 15;
  int s0 = blockIdx.x * 32, d0 = blockIdx.y * 32;
  int tx = threadIdx.x, ty = threadIdx.y;
  #pragma unroll
  for (int j = 0; j < 4; ++j)
    tile[ty + j*8][tx] = qkv[(size_t)(b*2048 + s0 + ty + j*8) * 3072 + 2048 + h*64 + d0 + tx];
  __syncthreads();
  #pragma unroll
  for (int j = 0; j < 4; ++j)
    vt[(size_t)(bh*64 + d0 + ty + j*8) * 2048 + s0 + tx] = tile[tx][ty + j*8];
}

// ---------------- GEMM: C[M][N] = A[M][K](bf16) @ BT[N][K](bf16)^T ---------
// 128x128 tile, BK=64, 4 waves (2x2), m97 2-barrier loop, 4 blocks/CU.
// EPI: 0 = bf16 (acc+bias), Q-cols (<1024) pre-scaled by QSCALE   (qkv)
//      2 = gelu(acc+bias) bf16                                    (fc)
//      4 = raw bf16 partial to o[blockIdx.z]   (split-K; bias in LN fuse)
#define GBM 128
#define GBN 128
#define GBK 64

__global__ __launch_bounds__(256, 4) void gemm_bf16(
    const short* __restrict__ A, const short* __restrict__ BT,
    const float* __restrict__ bias,
    void* __restrict__ out, void* __restrict__ out2,
    void* __restrict__ out3, void* __restrict__ out4,
    int M, int N, int K, int EPI, int KS)
{
  __shared__ __attribute__((aligned(16))) short smem[GBM*GBK*2];  // 32 KB
  short* sA = smem;                 // 16 KB, rows of 64 shorts, XOR-swizzled slots
  short* sB = smem + GBM*GBK;       // 16 KB
  const int t = threadIdx.x;
  const int lane = t & 63;
  const int w = t >> 6;
  const int wr = w >> 1, wc = w & 1;            // 2x2 wave grid, each wave 64x64
  const int lrow = lane & 15;
  const int lk = lane >> 4;

  // bijective XCD-chunked remap: XCD x computes a contiguous wg range
  const int gx = gridDim.x;
  const int nwg = gx * gridDim.y;               // all grids here: nwg % 8 == 0
  const int P = blockIdx.y * gx + blockIdx.x;
  const int wg = (P & 7) * (nwg >> 3) + (P >> 3);
  const int m0 = (wg / gx) * GBM, n0 = (wg % gx) * GBN;

  const int Kspl = K / KS;
  const int kbeg = blockIdx.z * Kspl;
  const int NT = Kspl / GBK;

  // hoisted staging pointers (advance += GBK per K-tile) and LDS dests
  const short* gA[4]; const short* gB[4]; int ldo[4];
  #pragma unroll
  for (int r = 0; r < 4; ++r){
    int o = r * 4096 + t * 16;                  // linear LDS byte offset
    int row = o >> 7;                           // 128 B per row
    int lsl = ((o >> 4) & 7) ^ (row & 7);       // inverse-swizzled source chunk
    ldo[r] = o;
    gA[r] = A  + (size_t)(m0 + row) * K + kbeg + lsl * 8;
    gB[r] = BT + (size_t)(n0 + row) * K + kbeg + lsl * 8;
  }

  // hoisted swizzled ds_read offsets (in shorts)
  int aoff[2][4], boff[2][4];
  #pragma unroll
  for (int kc = 0; kc < 2; ++kc){
    #pragma unroll
    for (int i = 0; i < 4; ++i){
      int ra = wr*64 + i*16 + lrow;
      aoff[kc][i] = ra*64 + ((kc*4 + lk) ^ (ra & 7))*8;
      int rb = wc*64 + i*16 + lrow;
      boff[kc][i] = rb*64 + ((kc*4 + lk) ^ (rb & 7))*8;
    }
  }

  f32x4 acc[4][4] = {};

  for (int tt = 0; tt < NT; ++tt){
    __syncthreads();                            // prior reads done before overwrite
    #pragma unroll
    for (int r = 0; r < 4; ++r) gload_lds16(gA[r], (char*)sA + ldo[r]);
    #pragma unroll
    for (int r = 0; r < 4; ++r) gload_lds16(gB[r], (char*)sB + ldo[r]);
    #pragma unroll
    for (int r = 0; r < 4; ++r){ gA[r] += GBK; gB[r] += GBK; }
    __syncthreads();                            // drains vmcnt before barrier

    #pragma unroll
    for (int kc = 0; kc < 2; ++kc){
      s16x8 af[4], bf[4];
      #pragma unroll
      for (int rt = 0; rt < 4; ++rt) af[rt] = *(const s16x8*)&sA[aoff[kc][rt]];
      #pragma unroll
      for (int ct = 0; ct < 4; ++ct) bf[ct] = *(const s16x8*)&sB[boff[kc][ct]];
      #pragma unroll
      for (int rt = 0; rt < 4; ++rt)
        #pragma unroll
        for (int ct = 0; ct < 4; ++ct)
          acc[rt][ct] = __builtin_amdgcn_mfma_f32_16x16x32_bf16(af[rt], bf[ct], acc[rt][ct], 0, 0, 0);
    }
  }

  // ---- epilogue: bf16 values -> LDS re-layout -> coalesced dwordx4 stores
  __syncthreads();                              // all waves done reading sA/sB
  #pragma unroll
  for (int rt = 0; rt < 4; ++rt){
    #pragma unroll
    for (int ct = 0; ct < 4; ++ct){
      #pragma unroll
      for (int r = 0; r < 4; ++r){
        int row = wr*64 + rt*16 + lk*4 + r;     // C/D: row=(lane>>4)*4+reg
        int col = wc*64 + ct*16 + lrow;         //      col=lane&15
        float v = acc[rt][ct][r];
        if (EPI != 4){
          v += bias[n0 + col];
          if (EPI == 0){
            if (n0 + col < 1024) v *= QSCALE;   // fold attn scale*log2e into Q
          } else {
            v = 0.5f * v * (1.0f + erff(v * 0.70710678118654752f));  // gelu
          }
        }
        int off = row*256 + ((col*2) ^ (((row >> 2) & 7) << 5));  // swizzled
        *(short*)((char*)smem + off) = f2bf(v);
      }
    }
  }
  __syncthreads();
  void* pz = (blockIdx.z == 0) ? out : (blockIdx.z == 1) ? out2
           : (blockIdx.z == 2) ? out3 : out4;
  short* outp = (EPI == 4) ? (short*)pz : (short*)out;
  #pragma unroll
  for (int j = 0; j < 8; ++j){
    int L = j*4096 + t*16;                      // logical byte offset in tile
    int row = L >> 8;                           // 256 B per logical row
    int cb  = L & 255;
    int phys = row*256 + (cb ^ (((row >> 2) & 7) << 5));   // 16B chunk intact
    s16x8 vv = *(const s16x8*)((char*)smem + phys);
    *(s16x8*)(outp + (size_t)(m0 + row) * N + n0 + (cb >> 1)) = vv;
  }
}

// ---------------- attention (causal), no-max softmax, 8-wave split pairs ----
// Block = 512 threads (8 waves). Waves 0-3 own q-tile A=pairi (rows w*16);
// waves 4-7 own q-tile B=31-pairi. ONE k-loop over tiles 0..31-pairi; A-waves
// compute only while ktile <= pairi (barriers always joint). K/V tiles staged
// once per tile (1 round each at 512 threads), counted vmcnt(2) pipeline.
// 512 blocks; all blocks of one (b,h) share an XCD (P%8); blocks P and P+256
// have complementary pairi -> per-CU tile cost constant (49).
__global__ __launch_bounds__(512, 4) void attn_kernel(
    const short* __restrict__ qkv, const short* __restrict__ vt,
    short* __restrict__ ob)
{
  const int P = blockIdx.x;
  const int xcd = P & 7;
  const int idx = P >> 3;               // 0..63
  const int raw = idx & 15;
  const int grp = idx >> 4;             // 0..3
  const int pairi = (grp & 2) ? (15 - raw) : raw;   // CU-pair balancing
  const int bh = xcd + (grp << 3);
  const int b = bh >> 4, h = bh & 15;
  const int t  = threadIdx.x;
  const int lane = t & 63;
  const int w = t >> 6;                 // 0..7
  const int lrow = lane & 15, lk = lane >> 4;

  __shared__ short sK[2][64*64];        // 2 x 8 KB, rows of 64 shorts, XOR-swizzled
  __shared__ short sV[2][64*64];        // 2 x 8 KB
  __shared__ short sP[8][16][68];       // per-wave P tile, +4 shorts pad

  s16x8 bones;                          // all-ones bf16 B fragment
  #pragma unroll
  for (int i = 0; i < 8; ++i) bones[i] = (short)0x3F80;

  // hoisted staging pointers: one 16B chunk per thread per tile
  const int so = t*16;                  // LDS byte offset (8 KB tile, 512 thr)
  const int srow = so >> 7;             // 128 B per row
  const int slsl = ((so >> 4) & 7) ^ (srow & 7);
  const short* kptr = qkv + (size_t)(b*2048)*3072 + 1024 + h*64
                      + (size_t)srow*3072 + slsl*8;
  const short* vptr = vt + (size_t)((b*16 + h)*64 + srow)*2048 + slsl*8;

  // hoisted swizzled read offsets (K and V tiles share layout)
  int kvoff[2][4];
  #pragma unroll
  for (int kc = 0; kc < 2; ++kc)
    #pragma unroll
    for (int i = 0; i < 4; ++i){
      int row = i*16 + lrow;
      kvoff[kc][i] = row*64 + ((kc*4 + lk) ^ (row & 7))*8;
    }

  const int set = w >> 2;               // 0 = A (short), 1 = B (long)
  const int qt = set ? (31 - pairi) : pairi;
  const int qbase = qt*64 + (w & 3)*16;
  const int ntSelf = qt + 1;            // this wave computes tiles < ntSelf
  const int ntB = 32 - pairi;           // loop bound (long set's tile count)

  s16x8 aq[2];
  #pragma unroll
  for (int kc = 0; kc < 2; ++kc)
    aq[kc] = *(const s16x8*)(qkv + (size_t)(b*2048 + qbase + lrow)*3072 + h*64 + kc*32 + lk*8);

  f32x4 oacc[4] = {};
  f32x4 sumacc = {};

  auto stage = [&](int buf){
    gload_lds16(kptr, (char*)sK[buf] + so);
    gload_lds16(vptr, (char*)sV[buf] + so);
    kptr += 64*3072;                    // next k-tile: +64 K-rows
    vptr += 64;                         // next k-tile: +64 V^T cols
  };

  stage(0);                             // prologue (2 loads in flight)
  int cur = 0;

  for (int ktile = 0; ktile < ntB; ++ktile){
    const int k0 = ktile * 64;
    if (ktile + 1 < ntB){
      stage(cur ^ 1);                   // issue next tile's 2 loads
      asm volatile("s_waitcnt vmcnt(2)" ::: "memory");   // tile `cur` landed
    } else {
      asm volatile("s_waitcnt vmcnt(0)" ::: "memory");
    }
    __builtin_amdgcn_s_barrier();       // acquire: all waves' tile-cur loads visible
    __builtin_amdgcn_sched_barrier(0);

    if (ktile < ntSelf){                // wave-uniform branch
      f32x4 sacc[4] = {};
      __builtin_amdgcn_s_setprio(1);
      #pragma unroll
      for (int kc = 0; kc < 2; ++kc){
        #pragma unroll
        for (int ct = 0; ct < 4; ++ct){
          s16x8 bk = *(const s16x8*)&sK[cur][kvoff[kc][ct]];
          sacc[ct] = __builtin_amdgcn_mfma_f32_16x16x32_bf16(aq[kc], bk, sacc[ct], 0, 0, 0);
        }
      }
      __builtin_amdgcn_s_setprio(0);

      const bool need_mask = (k0 + 63 > qbase);
      #pragma unroll
      for (int ct = 0; ct < 4; ++ct){
        #pragma unroll
        for (int r = 0; r < 4; ++r){
          float v = sacc[ct][r];                        // scale pre-folded in Q
          if (need_mask){
            int qi = qbase + lk*4 + r;
            int ki = k0 + ct*16 + lrow;
            if (ki > qi) v = -100000.0f;                // exp2 -> exactly 0
          }
          sP[w][lk*4 + r][ct*16 + lrow] = f2bf(exp2f(v));
        }
      }

      s16x8 pa[2];
      #pragma unroll
      for (int kc = 0; kc < 2; ++kc)
        pa[kc] = *(const s16x8*)&sP[w][lrow][kc*32 + lk*8];
      __builtin_amdgcn_s_setprio(1);
      #pragma unroll
      for (int dt = 0; dt < 4; ++dt){
        #pragma unroll
        for (int kc = 0; kc < 2; ++kc){
          s16x8 bv = *(const s16x8*)&sV[cur][kvoff[kc][dt]];
          oacc[dt] = __builtin_amdgcn_mfma_f32_16x16x32_bf16(pa[kc], bv, oacc[dt], 0, 0, 0);
        }
      }
      #pragma unroll
      for (int kc = 0; kc < 2; ++kc)
        sumacc = __builtin_amdgcn_mfma_f32_16x16x32_bf16(pa[kc], bones, sumacc, 0, 0, 0);
      __builtin_amdgcn_s_setprio(0);
    }

    __builtin_amdgcn_sched_barrier(0);
    __builtin_amdgcn_s_barrier();       // release: all waves done reading `cur`
    cur ^= 1;
  }

  #pragma unroll
  for (int r = 0; r < 4; ++r){
    float inv = 1.0f / sumacc[r];
    int row = b*2048 + qbase + lk*4 + r;
    #pragma unroll
    for (int dt = 0; dt < 4; ++dt){
      int col = h*64 + dt*16 + lrow;
      ob[(size_t)row * 1024 + col] = f2bf(oacc[dt][r] * inv);
    }
  }
}

// -------- LN fused with split-K4 reduce + residual --------------------------
// v = p0+p1+p2+p3 (bf16 partials) + bias + (resid_bf | resid_f); out = LN(v)
__global__ __launch_bounds__(256) void ln_fused(
    const short* __restrict__ p0, const short* __restrict__ p1,
    const short* __restrict__ p2, const short* __restrict__ p3,
    const float* __restrict__ bias,
    const short* __restrict__ resid_bf, const float* __restrict__ resid_f,
    const float* __restrict__ g, const float* __restrict__ b,
    void* __restrict__ out, int bf16_out)
{
  const int row = blockIdx.x;
  const int t = threadIdx.x;
  const size_t base = (size_t)row*1024 + t*4;
  short4 a0 = *(const short4*)(p0 + base);
  short4 a1 = *(const short4*)(p1 + base);
  short4 a2 = *(const short4*)(p2 + base);
  short4 a3 = *(const short4*)(p3 + base);
  float4 bi = *(const float4*)(bias + t*4);
  float r0, r1, r2, r3;
  if (resid_bf){
    short4 rr = *(const short4*)(resid_bf + base);
    r0 = bf2f(rr.x); r1 = bf2f(rr.y); r2 = bf2f(rr.z); r3 = bf2f(rr.w);
  } else {
    float4 rr = *(const float4*)(resid_f + base);
    r0 = rr.x; r1 = rr.y; r2 = rr.z; r3 = rr.w;
  }
  float v0 = bf2f(a0.x) + bf2f(a1.x) + bf2f(a2.x) + bf2f(a3.x) + bi.x + r0;
  float v1 = bf2f(a0.y) + bf2f(a1.y) + bf2f(a2.y) + bf2f(a3.y) + bi.y + r1;
  float v2 = bf2f(a0.z) + bf2f(a1.z) + bf2f(a2.z) + bf2f(a3.z) + bi.z + r2;
  float v3 = bf2f(a0.w) + bf2f(a1.w) + bf2f(a2.w) + bf2f(a3.w) + bi.w + r3;
  float s = v0 + v1 + v2 + v3;
  float q = v0*v0 + v1*v1 + v2*v2 + v3*v3;
  #pragma unroll
  for (int off = 1; off < 64; off <<= 1){
    s += __shfl_xor(s, off, 64);
    q += __shfl_xor(q, off, 64);
  }
  __shared__ float ss[4], sq[4];
  if ((t & 63) == 0){ ss[t >> 6] = s; sq[t >> 6] = q; }
  __syncthreads();
  s = ss[0] + ss[1] + ss[2] + ss[3];
  q = sq[0] + sq[1] + sq[2] + sq[3];
  float mu = s * (1.0f/1024.0f);
  float var = q * (1.0f/1024.0f) - mu*mu;
  float rs = rsqrtf(var + 1e-5f);
  float4 gg = *(const float4*)(g + t*4);
  float4 bb = *(const float4*)(b + t*4);
  float o0 = (v0 - mu)*rs*gg.x + bb.x;
  float o1 = (v1 - mu)*rs*gg.y + bb.y;
  float o2 = (v2 - mu)*rs*gg.z + bb.z;
  float o3 = (v3 - mu)*rs*gg.w + bb.w;
  if (bf16_out){
    short4 o; o.x = f2bf(o0); o.y = f2bf(o1); o.z = f2bf(o2); o.w = f2bf(o3);
    *(short4*)((short*)out + base) = o;
  } else {
    float4 o = {o0, o1, o2, o3};
    *(float4*)((float*)out + base) = o;
  }
}

// ---------------------------------------------------------------------------
extern "C" void kernel_launch(void* const* d_in, const int* in_sizes, int n_in,
                              void* d_out, int out_size, void* d_ws, size_t ws_size,
                              hipStream_t stream) {
  const float* x      = (const float*)d_in[0];
  const float* w_attn = (const float*)d_in[1];
  const float* b_attn = (const float*)d_in[2];
  const float* w_o    = (const float*)d_in[3];
  const float* b_o    = (const float*)d_in[4];
  const float* ln1_g  = (const float*)d_in[5];
  const float* ln1_b  = (const float*)d_in[6];
  const float* w_fc   = (const float*)d_in[7];
  const float* b_fc   = (const float*)d_in[8];
  const float* w_pr   = (const float*)d_in[9];
  const float* b_pr   = (const float*)d_in[10];
  const float* ln2_g  = (const float*)d_in[11];
  const float* ln2_b  = (const float*)d_in[12];

  char* ws = (char*)d_ws;
  const size_t MB = 1048576;
  // lifetimes: high-water 96 MiB
  short* waT  = (short*)(ws + 0);          // 6 MiB  (steps 1-2)
  short* wfT  = (short*)(ws + 6*MB);       // 8 MiB  (steps 1-7)
  short* wpT  = (short*)(ws + 14*MB);      // 8 MiB  (steps 1-8)
  short* woT  = (short*)(ws + 22*MB);      // 2 MiB  (steps 1-5)
  short* xb   = (short*)(ws + 24*MB);      // 8 MiB  (steps 1-2)
  short* vt   = (short*)(ws + 24*MB);      // 8 MiB  (steps 3-4)
  short* pp2  = (short*)(ws + 24*MB);      // 8 MiB  (steps 5-6, 8-9)
  short* qkvb = (short*)(ws + 32*MB);      // 24 MiB (steps 2-4)
  short* fb   = (short*)(ws + 32*MB);      // 32 MiB (steps 7-8)
  short* ob   = (short*)(ws + 56*MB);      // 8 MiB  (steps 4-5)
  short* pp0  = (short*)(ws + 64*MB);      // 8 MiB  (steps 5-6, 8-9)
  short* pp1  = (short*)(ws + 72*MB);      // 8 MiB
  short* nb   = (short*)(ws + 80*MB);      // 8 MiB  (steps 6-9)
  short* pp3  = (short*)(ws + 88*MB);      // 8 MiB  (steps 5-6, 8-9)

  const int M = 4096;

  // 1. consolidated prep: x->bf16 + all 4 weight transposes (1 dispatch)
  prep_all<<<dim3(16384), dim3(256), 0, stream>>>(
      x, w_attn, w_o, w_fc, w_pr, xb, waT, woT, wfT, wpT);
  // 2. qkv = x @ w_attn + b_attn (bf16 out, Q pre-scaled); 24x32 = 768 blocks
  gemm_bf16<<<dim3(3072/GBN, M/GBM), dim3(256), 0, stream>>>(
      xb, waT, b_attn, qkvb, nullptr, nullptr, nullptr, M, 3072, 1024, 0, 1);
  // 3. vt = transpose of V per (b,h)
  vtrans<<<dim3(2048/32, 64/32, 32), dim3(32,8), 0, stream>>>(qkvb, vt);
  // 4. attention -> ob (bf16); 8-wave split pairs, 512 blocks x 512 threads
  attn_kernel<<<dim3(512), dim3(512), 0, stream>>>(qkvb, vt, ob);
  // 5. o-proj split-K4: pp0..3 = ob @ w_o partials (bf16); 8x32x4 = 1024 blocks
  gemm_bf16<<<dim3(1024/GBN, M/GBM, 4), dim3(256), 0, stream>>>(
      ob, woT, nullptr, pp0, pp1, pp2, pp3, M, 1024, 1024, 4, 4);
  // 6. n = LN(pp* + b_o + x) -> nb (bf16)
  ln_fused<<<dim3(M), dim3(256), 0, stream>>>(pp0, pp1, pp2, pp3, b_o,
                                              nullptr, x, ln1_g, ln1_b, nb, 1);
  // 7. f = gelu(n @ w_fc + b_fc) -> fb (bf16); 32x32 = 1024 blocks (4/CU)
  gemm_bf16<<<dim3(4096/GBN, M/GBM), dim3(256), 0, stream>>>(
      nb, wfT, b_fc, fb, nullptr, nullptr, nullptr, M, 4096, 1024, 2, 1);
  // 8. r2 split-K4: pp0..3 = fb @ w_pr partials (bf16); 8x32x4 = 1024 blocks
  gemm_bf16<<<dim3(1024/GBN, M/GBM, 4), dim3(256), 0, stream>>>(
      fb, wpT, nullptr, pp0, pp1, pp2, pp3, M, 1024, 4096, 4, 4);
  // 9. h = LN(pp* + b_pr + nb) -> d_out (f32)
  ln_fused<<<dim3(M), dim3(256), 0, stream>>>(pp0, pp1, pp2, pp3, b_pr,
                                              nb, nullptr, ln2_g, ln2_b, d_out, 0);
}

// Round 21
// 247.017 us; speedup vs baseline: 1.0383x; 1.0081x over previous
//
#include <hip/hip_runtime.h>
#include <stdint.h>
#include <math.h>

// ---------------------------------------------------------------------------
// Transformer block (B=2, S=2048, D=1024, H=16, hd=64, F=4096), post-LN.
// bf16 MFMA for all matmuls, fp32 accumulate. Threshold is 2% of |ref|max.
// GEMMs: 128x128 tile, BK=64, m97 2-barrier loop, 4 blocks/CU; co-resident
//        blocks phase-staggered via s_sleep to break the stage/drain convoy.
// Attention: no-max softmax via exp2 (scale pre-folded into Q); 8-wave split
//        pairs; counted-vmcnt pipeline.
// Prep: single consolidated kernel (cvt + 4 weight transposes).
// ---------------------------------------------------------------------------

typedef __attribute__((ext_vector_type(4))) float f32x4;
typedef __attribute__((ext_vector_type(8))) short s16x8;

__device__ __forceinline__ float bf2f(short s){
  unsigned u = ((unsigned)(unsigned short)s) << 16;
  return __builtin_bit_cast(float, u);
}
__device__ __forceinline__ short f2bf(float f){
  unsigned u = __builtin_bit_cast(unsigned, f);
  unsigned r = (u + 0x7fffu + ((u >> 16) & 1u)) >> 16;   // RNE
  return (short)(unsigned short)r;
}

__device__ __forceinline__ void gload_lds16(const void* gp, void* lp){
  __builtin_amdgcn_global_load_lds(
      (__attribute__((address_space(1))) void*)const_cast<void*>(gp),
      (__attribute__((address_space(3))) void*)lp,
      16, 0, 0);
}

#define QSCALE 0.18033688f   // 0.125 * log2(e): folded into Q so attn uses exp2

// ---------------- consolidated prep: cvt x->bf16 + 4 weight transposes -----
// blockIdx regions: [0,4096) cvt | [4096,7168) waT | [7168,8192) woT
//                   [8192,12288) wfT | [12288,16384) wpT
__global__ __launch_bounds__(256) void prep_all(
    const float* __restrict__ x, const float* __restrict__ w_attn,
    const float* __restrict__ w_o, const float* __restrict__ w_fc,
    const float* __restrict__ w_pr,
    short* __restrict__ xb, short* __restrict__ waT, short* __restrict__ woT,
    short* __restrict__ wfT, short* __restrict__ wpT)
{
  const int bid = blockIdx.x;
  const int t = threadIdx.x;
  if (bid < 4096){                              // cvt region: 1024 elems/block
    int i = bid*1024 + t*4;
    float4 v = *(const float4*)(x + i);
    short4 o; o.x = f2bf(v.x); o.y = f2bf(v.y); o.z = f2bf(v.z); o.w = f2bf(v.w);
    *(short4*)(xb + i) = o;
    return;
  }
  const float* in; short* out; int R, C, q;
  if (bid < 7168)      { in = w_attn; out = waT; R = 1024; C = 3072; q = bid - 4096; }
  else if (bid < 8192) { in = w_o;    out = woT; R = 1024; C = 1024; q = bid - 7168; }
  else if (bid < 12288){ in = w_fc;   out = wfT; R = 1024; C = 4096; q = bid - 8192; }
  else                 { in = w_pr;   out = wpT; R = 4096; C = 1024; q = bid - 12288; }
  const int ctiles = C >> 5;
  const int r0 = (q / ctiles) * 32, c0 = (q % ctiles) * 32;
  __shared__ float tile[32][33];
  const int tx = t & 31, ty = t >> 5;           // 32x8
  #pragma unroll
  for (int j = 0; j < 4; ++j)
    tile[ty + j*8][tx] = in[(size_t)(r0 + ty + j*8) * C + c0 + tx];
  __syncthreads();
  #pragma unroll
  for (int j = 0; j < 4; ++j)
    out[(size_t)(c0 + ty + j*8) * R + r0 + tx] = f2bf(tile[tx][ty + j*8]);
}

// ---------------- V transpose: qkv[b*2048+s][2048+h*64+d] -> vt[(bh*64+d)][s]
__global__ __launch_bounds__(256) void vtrans(const short* __restrict__ qkv,
                                              short* __restrict__ vt){
  __shared__ short tile[32][33];
  int bh = blockIdx.z; int b = bh >> 4, h = bh & 15;
  int s0 = blockIdx.x * 32, d0 = blockIdx.y * 32;
  int tx = threadIdx.x, ty = threadIdx.y;
  #pragma unroll
  for (int j = 0; j < 4; ++j)
    tile[ty + j*8][tx] = qkv[(size_t)(b*2048 + s0 + ty + j*8) * 3072 + 2048 + h*64 + d0 + tx];
  __syncthreads();
  #pragma unroll
  for (int j = 0; j < 4; ++j)
    vt[(size_t)(bh*64 + d0 + ty + j*8) * 2048 + s0 + tx] = tile[tx][ty + j*8];
}

// ---------------- GEMM: C[M][N] = A[M][K](bf16) @ BT[N][K](bf16)^T ---------
// 128x128 tile, BK=64, 4 waves (2x2), m97 2-barrier loop, 4 blocks/CU.
// Co-resident blocks staggered ~1/4 tile period apart (s_sleep, timing-only).
// EPI: 0 = bf16 (acc+bias), Q-cols (<1024) pre-scaled by QSCALE   (qkv)
//      2 = gelu(acc+bias) bf16                                    (fc)
//      4 = raw bf16 partial to o[blockIdx.z]   (split-K; bias in LN fuse)
#define GBM 128
#define GBN 128
#define GBK 64

__global__ __launch_bounds__(256, 4) void gemm_bf16(
    const short* __restrict__ A, const short* __restrict__ BT,
    const float* __restrict__ bias,
    void* __restrict__ out, void* __restrict__ out2,
    void* __restrict__ out3, void* __restrict__ out4,
    int M, int N, int K, int EPI, int KS)
{
  __shared__ __attribute__((aligned(16))) short smem[GBM*GBK*2];  // 32 KB
  short* sA = smem;                 // 16 KB, rows of 64 shorts, XOR-swizzled slots
  short* sB = smem + GBM*GBK;       // 16 KB
  const int t = threadIdx.x;
  const int lane = t & 63;
  const int w = t >> 6;
  const int wr = w >> 1, wc = w & 1;            // 2x2 wave grid, each wave 64x64
  const int lrow = lane & 15;
  const int lk = lane >> 4;

  // bijective XCD-chunked remap: XCD x computes a contiguous wg range
  const int gx = gridDim.x;
  const int nwg = gx * gridDim.y;               // all grids here: nwg % 8 == 0
  const int P = blockIdx.y * gx + blockIdx.x;
  const int wg = (P & 7) * (nwg >> 3) + (P >> 3);
  const int m0 = (wg / gx) * GBM, n0 = (wg % gx) * GBN;

  // phase stagger: co-resident blocks (occupancy rounds) offset ~640 cyc apart
  {
    int lin = blockIdx.z * nwg + P;
    int ph = (lin >> 8) & 3;
    switch (ph){                                // s_sleep needs a literal imm
      case 1: __builtin_amdgcn_s_sleep(10); break;   // ~640 cyc
      case 2: __builtin_amdgcn_s_sleep(20); break;   // ~1280 cyc
      case 3: __builtin_amdgcn_s_sleep(30); break;   // ~1920 cyc
      default: break;
    }
  }

  const int Kspl = K / KS;
  const int kbeg = blockIdx.z * Kspl;
  const int NT = Kspl / GBK;

  // hoisted staging pointers (advance += GBK per K-tile) and LDS dests
  const short* gA[4]; const short* gB[4]; int ldo[4];
  #pragma unroll
  for (int r = 0; r < 4; ++r){
    int o = r * 4096 + t * 16;                  // linear LDS byte offset
    int row = o >> 7;                           // 128 B per row
    int lsl = ((o >> 4) & 7) ^ (row & 7);       // inverse-swizzled source chunk
    ldo[r] = o;
    gA[r] = A  + (size_t)(m0 + row) * K + kbeg + lsl * 8;
    gB[r] = BT + (size_t)(n0 + row) * K + kbeg + lsl * 8;
  }

  // hoisted swizzled ds_read offsets (in shorts)
  int aoff[2][4], boff[2][4];
  #pragma unroll
  for (int kc = 0; kc < 2; ++kc){
    #pragma unroll
    for (int i = 0; i < 4; ++i){
      int ra = wr*64 + i*16 + lrow;
      aoff[kc][i] = ra*64 + ((kc*4 + lk) ^ (ra & 7))*8;
      int rb = wc*64 + i*16 + lrow;
      boff[kc][i] = rb*64 + ((kc*4 + lk) ^ (rb & 7))*8;
    }
  }

  f32x4 acc[4][4] = {};

  for (int tt = 0; tt < NT; ++tt){
    __syncthreads();                            // prior reads done before overwrite
    #pragma unroll
    for (int r = 0; r < 4; ++r) gload_lds16(gA[r], (char*)sA + ldo[r]);
    #pragma unroll
    for (int r = 0; r < 4; ++r) gload_lds16(gB[r], (char*)sB + ldo[r]);
    #pragma unroll
    for (int r = 0; r < 4; ++r){ gA[r] += GBK; gB[r] += GBK; }
    __syncthreads();                            // drains vmcnt before barrier

    #pragma unroll
    for (int kc = 0; kc < 2; ++kc){
      s16x8 af[4], bf[4];
      #pragma unroll
      for (int rt = 0; rt < 4; ++rt) af[rt] = *(const s16x8*)&sA[aoff[kc][rt]];
      #pragma unroll
      for (int ct = 0; ct < 4; ++ct) bf[ct] = *(const s16x8*)&sB[boff[kc][ct]];
      #pragma unroll
      for (int rt = 0; rt < 4; ++rt)
        #pragma unroll
        for (int ct = 0; ct < 4; ++ct)
          acc[rt][ct] = __builtin_amdgcn_mfma_f32_16x16x32_bf16(af[rt], bf[ct], acc[rt][ct], 0, 0, 0);
    }
  }

  // ---- epilogue: bf16 values -> LDS re-layout -> coalesced dwordx4 stores
  __syncthreads();                              // all waves done reading sA/sB
  #pragma unroll
  for (int rt = 0; rt < 4; ++rt){
    #pragma unroll
    for (int ct = 0; ct < 4; ++ct){
      #pragma unroll
      for (int r = 0; r < 4; ++r){
        int row = wr*64 + rt*16 + lk*4 + r;     // C/D: row=(lane>>4)*4+reg
        int col = wc*64 + ct*16 + lrow;         //      col=lane&15
        float v = acc[rt][ct][r];
        if (EPI != 4){
          v += bias[n0 + col];
          if (EPI == 0){
            if (n0 + col < 1024) v *= QSCALE;   // fold attn scale*log2e into Q
          } else {
            v = 0.5f * v * (1.0f + erff(v * 0.70710678118654752f));  // gelu
          }
        }
        int off = row*256 + ((col*2) ^ (((row >> 2) & 7) << 5));  // swizzled
        *(short*)((char*)smem + off) = f2bf(v);
      }
    }
  }
  __syncthreads();
  void* pz = (blockIdx.z == 0) ? out : (blockIdx.z == 1) ? out2
           : (blockIdx.z == 2) ? out3 : out4;
  short* outp = (EPI == 4) ? (short*)pz : (short*)out;
  #pragma unroll
  for (int j = 0; j < 8; ++j){
    int L = j*4096 + t*16;                      // logical byte offset in tile
    int row = L >> 8;                           // 256 B per logical row
    int cb  = L & 255;
    int phys = row*256 + (cb ^ (((row >> 2) & 7) << 5));   // 16B chunk intact
    s16x8 vv = *(const s16x8*)((char*)smem + phys);
    *(s16x8*)(outp + (size_t)(m0 + row) * N + n0 + (cb >> 1)) = vv;
  }
}

// ---------------- attention (causal), no-max softmax, 8-wave split pairs ----
// Block = 512 threads (8 waves). Waves 0-3 own q-tile A=pairi (rows w*16);
// waves 4-7 own q-tile B=31-pairi. ONE k-loop over tiles 0..31-pairi; A-waves
// compute only while ktile <= pairi (barriers always joint). K/V tiles staged
// once per tile (1 round each at 512 threads), counted vmcnt(2) pipeline.
// 512 blocks; all blocks of one (b,h) share an XCD (P%8); blocks P and P+256
// have complementary pairi -> per-CU tile cost constant (49).
__global__ __launch_bounds__(512, 4) void attn_kernel(
    const short* __restrict__ qkv, const short* __restrict__ vt,
    short* __restrict__ ob)
{
  const int P = blockIdx.x;
  const int xcd = P & 7;
  const int idx = P >> 3;               // 0..63
  const int raw = idx & 15;
  const int grp = idx >> 4;             // 0..3
  const int pairi = (grp & 2) ? (15 - raw) : raw;   // CU-pair balancing
  const int bh = xcd + (grp << 3);
  const int b = bh >> 4, h = bh & 15;
  const int t  = threadIdx.x;
  const int lane = t & 63;
  const int w = t >> 6;                 // 0..7
  const int lrow = lane & 15, lk = lane >> 4;

  __shared__ short sK[2][64*64];        // 2 x 8 KB, rows of 64 shorts, XOR-swizzled
  __shared__ short sV[2][64*64];        // 2 x 8 KB
  __shared__ short sP[8][16][68];       // per-wave P tile, +4 shorts pad

  s16x8 bones;                          // all-ones bf16 B fragment
  #pragma unroll
  for (int i = 0; i < 8; ++i) bones[i] = (short)0x3F80;

  // hoisted staging pointers: one 16B chunk per thread per tile
  const int so = t*16;                  // LDS byte offset (8 KB tile, 512 thr)
  const int srow = so >> 7;             // 128 B per row
  const int slsl = ((so >> 4) & 7) ^ (srow & 7);
  const short* kptr = qkv + (size_t)(b*2048)*3072 + 1024 + h*64
                      + (size_t)srow*3072 + slsl*8;
  const short* vptr = vt + (size_t)((b*16 + h)*64 + srow)*2048 + slsl*8;

  // hoisted swizzled read offsets (K and V tiles share layout)
  int kvoff[2][4];
  #pragma unroll
  for (int kc = 0; kc < 2; ++kc)
    #pragma unroll
    for (int i = 0; i < 4; ++i){
      int row = i*16 + lrow;
      kvoff[kc][i] = row*64 + ((kc*4 + lk) ^ (row & 7))*8;
    }

  const int set = w >> 2;               // 0 = A (short), 1 = B (long)
  const int qt = set ? (31 - pairi) : pairi;
  const int qbase = qt*64 + (w & 3)*16;
  const int ntSelf = qt + 1;            // this wave computes tiles < ntSelf
  const int ntB = 32 - pairi;           // loop bound (long set's tile count)

  s16x8 aq[2];
  #pragma unroll
  for (int kc = 0; kc < 2; ++kc)
    aq[kc] = *(const s16x8*)(qkv + (size_t)(b*2048 + qbase + lrow)*3072 + h*64 + kc*32 + lk*8);

  f32x4 oacc[4] = {};
  f32x4 sumacc = {};

  auto stage = [&](int buf){
    gload_lds16(kptr, (char*)sK[buf] + so);
    gload_lds16(vptr, (char*)sV[buf] + so);
    kptr += 64*3072;                    // next k-tile: +64 K-rows
    vptr += 64;                         // next k-tile: +64 V^T cols
  };

  stage(0);                             // prologue (2 loads in flight)
  int cur = 0;

  for (int ktile = 0; ktile < ntB; ++ktile){
    const int k0 = ktile * 64;
    if (ktile + 1 < ntB){
      stage(cur ^ 1);                   // issue next tile's 2 loads
      asm volatile("s_waitcnt vmcnt(2)" ::: "memory");   // tile `cur` landed
    } else {
      asm volatile("s_waitcnt vmcnt(0)" ::: "memory");
    }
    __builtin_amdgcn_s_barrier();       // acquire: all waves' tile-cur loads visible
    __builtin_amdgcn_sched_barrier(0);

    if (ktile < ntSelf){                // wave-uniform branch
      f32x4 sacc[4] = {};
      __builtin_amdgcn_s_setprio(1);
      #pragma unroll
      for (int kc = 0; kc < 2; ++kc){
        #pragma unroll
        for (int ct = 0; ct < 4; ++ct){
          s16x8 bk = *(const s16x8*)&sK[cur][kvoff[kc][ct]];
          sacc[ct] = __builtin_amdgcn_mfma_f32_16x16x32_bf16(aq[kc], bk, sacc[ct], 0, 0, 0);
        }
      }
      __builtin_amdgcn_s_setprio(0);

      const bool need_mask = (k0 + 63 > qbase);
      #pragma unroll
      for (int ct = 0; ct < 4; ++ct){
        #pragma unroll
        for (int r = 0; r < 4; ++r){
          float v = sacc[ct][r];                        // scale pre-folded in Q
          if (need_mask){
            int qi = qbase + lk*4 + r;
            int ki = k0 + ct*16 + lrow;
            if (ki > qi) v = -100000.0f;                // exp2 -> exactly 0
          }
          sP[w][lk*4 + r][ct*16 + lrow] = f2bf(exp2f(v));
        }
      }

      s16x8 pa[2];
      #pragma unroll
      for (int kc = 0; kc < 2; ++kc)
        pa[kc] = *(const s16x8*)&sP[w][lrow][kc*32 + lk*8];
      __builtin_amdgcn_s_setprio(1);
      #pragma unroll
      for (int dt = 0; dt < 4; ++dt){
        #pragma unroll
        for (int kc = 0; kc < 2; ++kc){
          s16x8 bv = *(const s16x8*)&sV[cur][kvoff[kc][dt]];
          oacc[dt] = __builtin_amdgcn_mfma_f32_16x16x32_bf16(pa[kc], bv, oacc[dt], 0, 0, 0);
        }
      }
      #pragma unroll
      for (int kc = 0; kc < 2; ++kc)
        sumacc = __builtin_amdgcn_mfma_f32_16x16x32_bf16(pa[kc], bones, sumacc, 0, 0, 0);
      __builtin_amdgcn_s_setprio(0);
    }

    __builtin_amdgcn_sched_barrier(0);
    __builtin_amdgcn_s_barrier();       // release: all waves done reading `cur`
    cur ^= 1;
  }

  #pragma unroll
  for (int r = 0; r < 4; ++r){
    float inv = 1.0f / sumacc[r];
    int row = b*2048 + qbase + lk*4 + r;
    #pragma unroll
    for (int dt = 0; dt < 4; ++dt){
      int col = h*64 + dt*16 + lrow;
      ob[(size_t)row * 1024 + col] = f2bf(oacc[dt][r] * inv);
    }
  }
}

// -------- LN fused with split-K4 reduce + residual --------------------------
// v = p0+p1+p2+p3 (bf16 partials) + bias + (resid_bf | resid_f); out = LN(v)
__global__ __launch_bounds__(256) void ln_fused(
    const short* __restrict__ p0, const short* __restrict__ p1,
    const short* __restrict__ p2, const short* __restrict__ p3,
    const float* __restrict__ bias,
    const short* __restrict__ resid_bf, const float* __restrict__ resid_f,
    const float* __restrict__ g, const float* __restrict__ b,
    void* __restrict__ out, int bf16_out)
{
  const int row = blockIdx.x;
  const int t = threadIdx.x;
  const size_t base = (size_t)row*1024 + t*4;
  short4 a0 = *(const short4*)(p0 + base);
  short4 a1 = *(const short4*)(p1 + base);
  short4 a2 = *(const short4*)(p2 + base);
  short4 a3 = *(const short4*)(p3 + base);
  float4 bi = *(const float4*)(bias + t*4);
  float r0, r1, r2, r3;
  if (resid_bf){
    short4 rr = *(const short4*)(resid_bf + base);
    r0 = bf2f(rr.x); r1 = bf2f(rr.y); r2 = bf2f(rr.z); r3 = bf2f(rr.w);
  } else {
    float4 rr = *(const float4*)(resid_f + base);
    r0 = rr.x; r1 = rr.y; r2 = rr.z; r3 = rr.w;
  }
  float v0 = bf2f(a0.x) + bf2f(a1.x) + bf2f(a2.x) + bf2f(a3.x) + bi.x + r0;
  float v1 = bf2f(a0.y) + bf2f(a1.y) + bf2f(a2.y) + bf2f(a3.y) + bi.y + r1;
  float v2 = bf2f(a0.z) + bf2f(a1.z) + bf2f(a2.z) + bf2f(a3.z) + bi.z + r2;
  float v3 = bf2f(a0.w) + bf2f(a1.w) + bf2f(a2.w) + bf2f(a3.w) + bi.w + r3;
  float s = v0 + v1 + v2 + v3;
  float q = v0*v0 + v1*v1 + v2*v2 + v3*v3;
  #pragma unroll
  for (int off = 1; off < 64; off <<= 1){
    s += __shfl_xor(s, off, 64);
    q += __shfl_xor(q, off, 64);
  }
  __shared__ float ss[4], sq[4];
  if ((t & 63) == 0){ ss[t >> 6] = s; sq[t >> 6] = q; }
  __syncthreads();
  s = ss[0] + ss[1] + ss[2] + ss[3];
  q = sq[0] + sq[1] + sq[2] + sq[3];
  float mu = s * (1.0f/1024.0f);
  float var = q * (1.0f/1024.0f) - mu*mu;
  float rs = rsqrtf(var + 1e-5f);
  float4 gg = *(const float4*)(g + t*4);
  float4 bb = *(const float4*)(b + t*4);
  float o0 = (v0 - mu)*rs*gg.x + bb.x;
  float o1 = (v1 - mu)*rs*gg.y + bb.y;
  float o2 = (v2 - mu)*rs*gg.z + bb.z;
  float o3 = (v3 - mu)*rs*gg.w + bb.w;
  if (bf16_out){
    short4 o; o.x = f2bf(o0); o.y = f2bf(o1); o.z = f2bf(o2); o.w = f2bf(o3);
    *(short4*)((short*)out + base) = o;
  } else {
    float4 o = {o0, o1, o2, o3};
    *(float4*)((float*)out + base) = o;
  }
}

// ---------------------------------------------------------------------------
extern "C" void kernel_launch(void* const* d_in, const int* in_sizes, int n_in,
                              void* d_out, int out_size, void* d_ws, size_t ws_size,
                              hipStream_t stream) {
  const float* x      = (const float*)d_in[0];
  const float* w_attn = (const float*)d_in[1];
  const float* b_attn = (const float*)d_in[2];
  const float* w_o    = (const float*)d_in[3];
  const float* b_o    = (const float*)d_in[4];
  const float* ln1_g  = (const float*)d_in[5];
  const float* ln1_b  = (const float*)d_in[6];
  const float* w_fc   = (const float*)d_in[7];
  const float* b_fc   = (const float*)d_in[8];
  const float* w_pr   = (const float*)d_in[9];
  const float* b_pr   = (const float*)d_in[10];
  const float* ln2_g  = (const float*)d_in[11];
  const float* ln2_b  = (const float*)d_in[12];

  char* ws = (char*)d_ws;
  const size_t MB = 1048576;
  // lifetimes: high-water 96 MiB
  short* waT  = (short*)(ws + 0);          // 6 MiB  (steps 1-2)
  short* wfT  = (short*)(ws + 6*MB);       // 8 MiB  (steps 1-7)
  short* wpT  = (short*)(ws + 14*MB);      // 8 MiB  (steps 1-8)
  short* woT  = (short*)(ws + 22*MB);      // 2 MiB  (steps 1-5)
  short* xb   = (short*)(ws + 24*MB);      // 8 MiB  (steps 1-2)
  short* vt   = (short*)(ws + 24*MB);      // 8 MiB  (steps 3-4)
  short* pp2  = (short*)(ws + 24*MB);      // 8 MiB  (steps 5-6, 8-9)
  short* qkvb = (short*)(ws + 32*MB);      // 24 MiB (steps 2-4)
  short* fb   = (short*)(ws + 32*MB);      // 32 MiB (steps 7-8)
  short* ob   = (short*)(ws + 56*MB);      // 8 MiB  (steps 4-5)
  short* pp0  = (short*)(ws + 64*MB);      // 8 MiB  (steps 5-6, 8-9)
  short* pp1  = (short*)(ws + 72*MB);      // 8 MiB
  short* nb   = (short*)(ws + 80*MB);      // 8 MiB  (steps 6-9)
  short* pp3  = (short*)(ws + 88*MB);      // 8 MiB  (steps 5-6, 8-9)

  const int M = 4096;

  // 1. consolidated prep: x->bf16 + all 4 weight transposes (1 dispatch)
  prep_all<<<dim3(16384), dim3(256), 0, stream>>>(
      x, w_attn, w_o, w_fc, w_pr, xb, waT, woT, wfT, wpT);
  // 2. qkv = x @ w_attn + b_attn (bf16 out, Q pre-scaled); 24x32 = 768 blocks
  gemm_bf16<<<dim3(3072/GBN, M/GBM), dim3(256), 0, stream>>>(
      xb, waT, b_attn, qkvb, nullptr, nullptr, nullptr, M, 3072, 1024, 0, 1);
  // 3. vt = transpose of V per (b,h)
  vtrans<<<dim3(2048/32, 64/32, 32), dim3(32,8), 0, stream>>>(qkvb, vt);
  // 4. attention -> ob (bf16); 8-wave split pairs, 512 blocks x 512 threads
  attn_kernel<<<dim3(512), dim3(512), 0, stream>>>(qkvb, vt, ob);
  // 5. o-proj split-K4: pp0..3 = ob @ w_o partials (bf16); 8x32x4 = 1024 blocks
  gemm_bf16<<<dim3(1024/GBN, M/GBM, 4), dim3(256), 0, stream>>>(
      ob, woT, nullptr, pp0, pp1, pp2, pp3, M, 1024, 1024, 4, 4);
  // 6. n = LN(pp* + b_o + x) -> nb (bf16)
  ln_fused<<<dim3(M), dim3(256), 0, stream>>>(pp0, pp1, pp2, pp3, b_o,
                                              nullptr, x, ln1_g, ln1_b, nb, 1);
  // 7. f = gelu(n @ w_fc + b_fc) -> fb (bf16); 32x32 = 1024 blocks (4/CU)
  gemm_bf16<<<dim3(4096/GBN, M/GBM), dim3(256), 0, stream>>>(
      nb, wfT, b_fc, fb, nullptr, nullptr, nullptr, M, 4096, 1024, 2, 1);
  // 8. r2 split-K4: pp0..3 = fb @ w_pr partials (bf16); 8x32x4 = 1024 blocks
  gemm_bf16<<<dim3(1024/GBN, M/GBM, 4), dim3(256), 0, stream>>>(
      fb, wpT, nullptr, pp0, pp1, pp2, pp3, M, 1024, 4096, 4, 4);
  // 9. h = LN(pp* + b_pr + nb) -> d_out (f32)
  ln_fused<<<dim3(M), dim3(256), 0, stream>>>(pp0, pp1, pp2, pp3, b_pr,
                                              nb, nullptr, ln2_g, ln2_b, d_out, 0);
}